// Round 6
// baseline (577.400 us; speedup 1.0000x reference)
//
#include <hip/hip_runtime.h>
#include <hip/hip_fp16.h>

#define IN_F 128
#define OUT_F 32
#define R_NODES 128          // dst nodes per bucket (7 bits)
#define BKT_CAP 4096         // Poisson(2046)+45sigma; overflow handled anyway
#define OVF_CAP 4096
#define EPB 8192             // edges per build block
#define MAXNB 1024           // max buckets => n_nodes <= 131072
#define NPHASE 4             // src-phases in gather (L2 working-set blocking)

// ---------------------------------------------------------------------------
// Stage 1: src-degrees + bucket partition via BLOCK-LOCAL counting sort.
// (round-3 lesson: never grid-scatter 4B grains; chunked flush only.)
// in_cnt counts ONLY overflow edges; main in-degree is counted in gather.
// ---------------------------------------------------------------------------
__global__ __launch_bounds__(256) void build_kernel(
    const int* __restrict__ src, const int* __restrict__ dst,
    int* __restrict__ out_cnt, int* __restrict__ in_cnt,
    int* __restrict__ gcur, unsigned* __restrict__ bkt,
    int* __restrict__ ovf, int* __restrict__ ovf_cnt,
    int n_edges) {

    __shared__ unsigned sorted[EPB];        // 32 KB
    __shared__ unsigned short binof[EPB];   // 16 KB
    __shared__ int hist[MAXNB];
    __shared__ int lbase[MAXNB];
    __shared__ int gbase[MAXNB];
    __shared__ int wsum[4];

    int tid = threadIdx.x;
    int e0 = blockIdx.x * EPB;
    int ecnt = min(EPB, n_edges - e0);

    int b0 = tid * 4;
#pragma unroll
    for (int r = 0; r < 4; ++r) hist[b0 + r] = 0;
    __syncthreads();

    // pass 1: src-degree atomics + bin histogram
    for (int k = tid; k < ecnt; k += 256) {
        int e = e0 + k;
        int s = src[e], d = dst[e];
        atomicAdd(&out_cnt[s], 1);
        atomicAdd(&hist[d >> 7], 1);
    }
    __syncthreads();

    // block-wide exclusive scan of hist -> lbase; reserve global chunks
    int c[4]; int tsum = 0;
#pragma unroll
    for (int r = 0; r < 4; ++r) { c[r] = hist[b0 + r]; tsum += c[r]; }
    int lane = tid & 63, wid = tid >> 6;
    int scan = tsum;
    for (int off = 1; off < 64; off <<= 1) {
        int v = __shfl_up(scan, off, 64);
        if (lane >= off) scan += v;
    }
    if (lane == 63) wsum[wid] = scan;
    __syncthreads();
    int woff = 0;
    for (int w = 0; w < wid; ++w) woff += wsum[w];
    int run = woff + scan - tsum;
#pragma unroll
    for (int r = 0; r < 4; ++r) {
        lbase[b0 + r] = run;
        hist[b0 + r]  = run;                // becomes insertion cursor
        if (c[r] > 0) gbase[b0 + r] = atomicAdd(&gcur[b0 + r], c[r]);
        run += c[r];
    }
    __syncthreads();

    // pass 2: local counting-sort into LDS (edges re-read, L2-hot)
    for (int k = tid; k < ecnt; k += 256) {
        int e = e0 + k;
        int s = src[e], d = dst[e];
        int bin = d >> 7;
        int idx = atomicAdd(&hist[bin], 1);
        sorted[idx] = ((unsigned)s << 7) | (unsigned)(d & 127);
        binof[idx]  = (unsigned short)bin;
    }
    __syncthreads();

    // pass 3: chunked, mostly-coalesced flush
    for (int i = tid; i < ecnt; i += 256) {
        unsigned v = sorted[i];
        int bin = binof[i];
        int gpos = gbase[bin] + (i - lbase[bin]);
        if (gpos < BKT_CAP) {
            bkt[(size_t)bin * BKT_CAP + gpos] = v;
        } else {
            int d = bin * R_NODES + (int)(v & 127);
            atomicAdd(&in_cnt[d], 1);       // overflow-only in-degree
            int o = atomicAdd(ovf_cnt, 1);
            if (o < OVF_CAP) {
                ovf[2 * o]     = (int)(v >> 7);
                ovf[2 * o + 1] = d;
            }
        }
    }
}

// ---------------------------------------------------------------------------
// Stage 2: tmp(fp16) = (feat * outdeg^-1/2) @ W.  4 rows x 4 cols/thread.
// fp16 halves the gather's random working set (6.4 MB) and makes a row one
// 64B line. Precision: err std ~8e-5 per output vs 2.97e-2 threshold.
// ---------------------------------------------------------------------------
__global__ __launch_bounds__(256) void linear_kernel(const float* __restrict__ feat,
                                                     const float* __restrict__ weight,
                                                     const int* __restrict__ out_cnt,
                                                     __half* __restrict__ tmp, int n_nodes) {
    __shared__ float w[IN_F * OUT_F];
    {
        const float4* wg = (const float4*)weight;
        float4* wsh = (float4*)w;
        for (int i = threadIdx.x; i < IN_F * OUT_F / 4; i += 256) wsh[i] = wg[i];
    }
    __syncthreads();

    int q  = threadIdx.x >> 3;
    int cg = threadIdx.x & 7;
    int row0 = blockIdx.x * 128 + q * 4;
    if (row0 >= n_nodes) return;
    int rmax = n_nodes - row0;
    if (rmax > 4) rmax = 4;

    const float4* feat4 = (const float4*)feat;
    float4 acc[4];
#pragma unroll
    for (int r = 0; r < 4; ++r) acc[r] = make_float4(0.f, 0.f, 0.f, 0.f);

    for (int k4 = 0; k4 < IN_F / 4; ++k4) {
        float4 wv0 = *(const float4*)&w[(4 * k4 + 0) * OUT_F + 4 * cg];
        float4 wv1 = *(const float4*)&w[(4 * k4 + 1) * OUT_F + 4 * cg];
        float4 wv2 = *(const float4*)&w[(4 * k4 + 2) * OUT_F + 4 * cg];
        float4 wv3 = *(const float4*)&w[(4 * k4 + 3) * OUT_F + 4 * cg];
#pragma unroll
        for (int r = 0; r < 4; ++r) {
            int rr = (r < rmax) ? r : 0;
            float4 f = feat4[(size_t)(row0 + rr) * (IN_F / 4) + k4];
            acc[r].x += f.x * wv0.x + f.y * wv1.x + f.z * wv2.x + f.w * wv3.x;
            acc[r].y += f.x * wv0.y + f.y * wv1.y + f.z * wv2.y + f.w * wv3.y;
            acc[r].z += f.x * wv0.z + f.y * wv1.z + f.z * wv2.z + f.w * wv3.z;
            acc[r].w += f.x * wv0.w + f.y * wv1.w + f.z * wv2.w + f.w * wv3.w;
        }
    }

#pragma unroll
    for (int r = 0; r < 4; ++r) {
        if (r < rmax) {
            float sc = rsqrtf(fmaxf((float)out_cnt[row0 + r], 1.0f));
            union { __half h[4]; uint2 u; } pk;
            pk.h[0] = __float2half(acc[r].x * sc);
            pk.h[1] = __float2half(acc[r].y * sc);
            pk.h[2] = __float2half(acc[r].z * sc);
            pk.h[3] = __float2half(acc[r].w * sc);
            *(uint2*)&tmp[(size_t)(row0 + r) * OUT_F + 4 * cg] = pk.u;
        }
    }
}

// ---------------------------------------------------------------------------
// Stage 3: one 1024-thread block per 128-node bucket. Entries staged in LDS
// once; swept NPHASE times keeping only src in the current quarter ->
// active tmp slice 1.6 MB << 4 MB per-XCD L2 (round-5 lesson: random
// gathers beyond L2 run at ~425 GB/s HBM-random with no L3 help).
// LDS: acc 16K + ent 16K + lcnt 0.5K = 33 KB -> 2 blocks/CU = 32 waves.
// ---------------------------------------------------------------------------
__global__ __launch_bounds__(1024) void bucket_gather(const unsigned* __restrict__ bkt,
                                                      const int* __restrict__ gcur,
                                                      const int* __restrict__ in_cnt,
                                                      const __half* __restrict__ tmp,
                                                      float* __restrict__ out,
                                                      int* __restrict__ deg, int n_nodes) {
    __shared__ float acc[R_NODES * OUT_F];  // 16 KB
    __shared__ unsigned ent[BKT_CAP];       // 16 KB
    __shared__ int lcnt[R_NODES];
    int b = blockIdx.x;
    int n0 = b * R_NODES;
    int tid = threadIdx.x;

    int ecnt = min(gcur[b], BKT_CAP);
    {
        float4* a4 = (float4*)acc;
        for (int i = tid; i < R_NODES * OUT_F / 4; i += 1024)
            a4[i] = make_float4(0.f, 0.f, 0.f, 0.f);
        if (tid < R_NODES) lcnt[tid] = 0;
        for (int i = tid; i < ecnt; i += 1024) ent[i] = bkt[(size_t)b * BKT_CAP + i];
    }
    __syncthreads();

    int g = tid >> 5;    // edge-group 0..31
    int c = tid & 31;    // column
    int qsz = (n_nodes + NPHASE - 1) / NPHASE;

    for (int p = 0; p < NPHASE; ++p) {
        int lo = p * qsz;
        int hi = min(lo + qsz, n_nodes);
        for (int e = g; e < ecnt; e += 128) {
            bool ok[4]; int s[4], l[4]; float val[4];
#pragma unroll
            for (int k = 0; k < 4; ++k) {
                int ee = e + 32 * k;
                unsigned v = (ee < ecnt) ? ent[ee] : 0u;   // LDS broadcast read
                s[k] = (int)(v >> 7);
                l[k] = (int)(v & 127u);
                ok[k] = (ee < ecnt) && (s[k] >= lo) && (s[k] < hi);
            }
#pragma unroll
            for (int k = 0; k < 4; ++k)
                val[k] = ok[k] ? __half2float(tmp[(size_t)s[k] * OUT_F + c]) : 0.f;
#pragma unroll
            for (int k = 0; k < 4; ++k) {
                if (ok[k]) {
                    atomicAdd(&acc[l[k] * OUT_F + c], val[k]);
                    if (c == 0) atomicAdd(&lcnt[l[k]], 1);
                }
            }
        }
    }
    __syncthreads();

    int nmax = min(R_NODES, n_nodes - n0);
    for (int i = tid; i < nmax * OUT_F; i += 1024) {
        int ln = i >> 5;
        int node = n0 + ln;
        int d = lcnt[ln] + in_cnt[node];    // in_cnt holds overflow-only counts
        if ((i & 31) == 0) deg[node] = d;
        float sc = rsqrtf(fmaxf((float)d, 1.0f));
        out[(size_t)n0 * OUT_F + i] = acc[i] * sc;
    }
}

// ---------------------------------------------------------------------------
// Stage 3b: overflow edges — expected 0; correctness only.
// ---------------------------------------------------------------------------
__global__ void ovf_kernel(const int* __restrict__ ovf, const int* __restrict__ ovf_cnt,
                           const int* __restrict__ deg, const __half* __restrict__ tmp,
                           float* __restrict__ out) {
    int t = blockIdx.x * blockDim.x + threadIdx.x;
    int e = t >> 5, c = t & 31;
    int n = min(*ovf_cnt, OVF_CAP);
    if (e < n) {
        int s = ovf[2 * e], d = ovf[2 * e + 1];
        float scale = rsqrtf(fmaxf((float)deg[d], 1.0f));
        atomicAdd(&out[(size_t)d * OUT_F + c],
                  __half2float(tmp[(size_t)s * OUT_F + c]) * scale);
    }
}

// ---------------------------------------------------------------------------
// Fallback (ws too small): atomic scatter path.
// ---------------------------------------------------------------------------
__global__ void scatter_kernel(const int* __restrict__ src, const int* __restrict__ dst,
                               const __half* __restrict__ tmp, float* __restrict__ out,
                               int n_edges) {
    long long t = (long long)blockIdx.x * blockDim.x + threadIdx.x;
    int e = (int)(t >> 5);
    int c = (int)(t & (OUT_F - 1));
    if (e < n_edges) {
        atomicAdd(&out[(size_t)dst[e] * OUT_F + c],
                  __half2float(tmp[(size_t)src[e] * OUT_F + c]));
    }
}

__global__ void finalize_kernel(float* __restrict__ out, const int* __restrict__ in_cnt,
                                int n_total) {
    int t = blockIdx.x * blockDim.x + threadIdx.x;
    if (t < n_total) {
        out[t] *= rsqrtf(fmaxf((float)in_cnt[t >> 5], 1.0f));
    }
}

__global__ void degree_kernel(const int* __restrict__ src, const int* __restrict__ dst,
                              int* __restrict__ out_cnt, int* __restrict__ in_cnt,
                              int n_edges) {
    int i = blockIdx.x * blockDim.x + threadIdx.x;
    if (i < n_edges) {
        atomicAdd(&out_cnt[src[i]], 1);
        atomicAdd(&in_cnt[dst[i]], 1);
    }
}

extern "C" void kernel_launch(void* const* d_in, const int* in_sizes, int n_in,
                              void* d_out, int out_size, void* d_ws, size_t ws_size,
                              hipStream_t stream) {
    const float* feat   = (const float*)d_in[0];
    const int*   src    = (const int*)d_in[1];
    const int*   dst    = (const int*)d_in[2];
    const float* weight = (const float*)d_in[3];
    float*       out    = (float*)d_out;

    int n_nodes = in_sizes[0] / IN_F;   // 100000
    int n_edges = in_sizes[1];          // 1600000
    int n_buckets = (n_nodes + R_NODES - 1) / R_NODES;  // 782 (<= MAXNB)

    // ws layout: [out_cnt n][in_cnt n][gcur MAXNB][ovf_cnt 8][ovf 2*CAP][bkt][tmp fp16][deg n]
    int*      out_cnt = (int*)d_ws;
    int*      in_cnt  = out_cnt + n_nodes;
    int*      gcur    = in_cnt + n_nodes;
    int*      ovf_cnt = gcur + MAXNB;
    int*      ovf     = ovf_cnt + 8;
    unsigned* bkt     = (unsigned*)(ovf + 2 * OVF_CAP);
    __half*   tmp     = (__half*)(bkt + (size_t)n_buckets * BKT_CAP);
    int*      deg     = (int*)(tmp + (size_t)n_nodes * OUT_F);
    size_t    needed  = (char*)(deg + n_nodes) - (char*)d_ws;

    if (ws_size >= needed && n_buckets <= MAXNB) {
        hipMemsetAsync(out_cnt, 0, ((size_t)2 * n_nodes + MAXNB + 8) * sizeof(int), stream);
        build_kernel<<<(n_edges + EPB - 1) / EPB, 256, 0, stream>>>(
            src, dst, out_cnt, in_cnt, gcur, bkt, ovf, ovf_cnt, n_edges);
        linear_kernel<<<(n_nodes + 127) / 128, 256, 0, stream>>>(
            feat, weight, out_cnt, tmp, n_nodes);
        bucket_gather<<<n_buckets, 1024, 0, stream>>>(
            bkt, gcur, in_cnt, tmp, out, deg, n_nodes);
        ovf_kernel<<<OVF_CAP * 32 / 256, 256, 0, stream>>>(ovf, ovf_cnt, deg, tmp, out);
    } else {
        // fallback: atomic scatter
        __half* tmp_fb = (__half*)(ovf + 2 * OVF_CAP);
        hipMemsetAsync(out_cnt, 0, ((size_t)2 * n_nodes + MAXNB + 8) * sizeof(int), stream);
        hipMemsetAsync(d_out, 0, (size_t)out_size * sizeof(float), stream);
        degree_kernel<<<(n_edges + 255) / 256, 256, 0, stream>>>(src, dst, out_cnt, in_cnt, n_edges);
        linear_kernel<<<(n_nodes + 127) / 128, 256, 0, stream>>>(feat, weight, out_cnt, tmp_fb, n_nodes);
        long long st = (long long)n_edges * OUT_F;
        scatter_kernel<<<(int)((st + 255) / 256), 256, 0, stream>>>(src, dst, tmp_fb, out, n_edges);
        finalize_kernel<<<(n_nodes * OUT_F + 255) / 256, 256, 0, stream>>>(out, in_cnt, n_nodes * OUT_F);
    }
}

// Round 7
// 245.703 us; speedup vs baseline: 2.3500x; 2.3500x over previous
//
#include <hip/hip_runtime.h>
#include <hip/hip_fp16.h>

#define IN_F 128
#define OUT_F 32
#define R_NODES 128          // dst nodes per bucket (7 bits)
#define BKT_CAP 3072         // Poisson(2046)+23sigma; overflow handled anyway
#define OVF_CAP 4096
#define EPB 8192             // edges per build block
#define MAXNB 1024           // max buckets => n_nodes <= 131072

// ---------------------------------------------------------------------------
// Stage 1: src-degrees + bucket partition via BLOCK-LOCAL counting sort.
// (round-3 lesson: never grid-scatter 4B grains; chunked flush only.)
// in_cnt counts ONLY overflow edges; main in-degree comes from bucket_sort.
// ---------------------------------------------------------------------------
__global__ __launch_bounds__(256) void build_kernel(
    const int* __restrict__ src, const int* __restrict__ dst,
    int* __restrict__ out_cnt, int* __restrict__ in_cnt,
    int* __restrict__ gcur, unsigned* __restrict__ bkt,
    int* __restrict__ ovf, int* __restrict__ ovf_cnt,
    int n_edges) {

    __shared__ unsigned sorted[EPB];        // 32 KB
    __shared__ unsigned short binof[EPB];   // 16 KB
    __shared__ int hist[MAXNB];
    __shared__ int lbase[MAXNB];
    __shared__ int gbase[MAXNB];
    __shared__ int wsum[4];

    int tid = threadIdx.x;
    int e0 = blockIdx.x * EPB;
    int ecnt = min(EPB, n_edges - e0);

    int b0 = tid * 4;
#pragma unroll
    for (int r = 0; r < 4; ++r) hist[b0 + r] = 0;
    __syncthreads();

    // pass 1: src-degree atomics + bin histogram
    for (int k = tid; k < ecnt; k += 256) {
        int e = e0 + k;
        int s = src[e], d = dst[e];
        atomicAdd(&out_cnt[s], 1);
        atomicAdd(&hist[d >> 7], 1);
    }
    __syncthreads();

    // block-wide exclusive scan of hist -> lbase; reserve global chunks
    int c[4]; int tsum = 0;
#pragma unroll
    for (int r = 0; r < 4; ++r) { c[r] = hist[b0 + r]; tsum += c[r]; }
    int lane = tid & 63, wid = tid >> 6;
    int scan = tsum;
    for (int off = 1; off < 64; off <<= 1) {
        int v = __shfl_up(scan, off, 64);
        if (lane >= off) scan += v;
    }
    if (lane == 63) wsum[wid] = scan;
    __syncthreads();
    int woff = 0;
    for (int w = 0; w < wid; ++w) woff += wsum[w];
    int run = woff + scan - tsum;
#pragma unroll
    for (int r = 0; r < 4; ++r) {
        lbase[b0 + r] = run;
        hist[b0 + r]  = run;                // becomes insertion cursor
        if (c[r] > 0) gbase[b0 + r] = atomicAdd(&gcur[b0 + r], c[r]);
        run += c[r];
    }
    __syncthreads();

    // pass 2: local counting-sort into LDS (edges re-read, L2-hot)
    for (int k = tid; k < ecnt; k += 256) {
        int e = e0 + k;
        int s = src[e], d = dst[e];
        int bin = d >> 7;
        int idx = atomicAdd(&hist[bin], 1);
        sorted[idx] = ((unsigned)s << 7) | (unsigned)(d & 127);
        binof[idx]  = (unsigned short)bin;
    }
    __syncthreads();

    // pass 3: chunked, mostly-coalesced flush
    for (int i = tid; i < ecnt; i += 256) {
        unsigned v = sorted[i];
        int bin = binof[i];
        int gpos = gbase[bin] + (i - lbase[bin]);
        if (gpos < BKT_CAP) {
            bkt[(size_t)bin * BKT_CAP + gpos] = v;
        } else {
            int d = bin * R_NODES + (int)(v & 127);
            atomicAdd(&in_cnt[d], 1);       // overflow-only in-degree
            int o = atomicAdd(ovf_cnt, 1);
            if (o < OVF_CAP) {
                ovf[2 * o]     = (int)(v >> 7);
                ovf[2 * o + 1] = d;
            }
        }
    }
}

// ---------------------------------------------------------------------------
// Stage 2: per-bucket sort by local dst -> in-place CSR. One block/bucket.
// Histogram (int LDS atomics, ~3.2M total lane-ops vs the 51.2M fp-atomic
// trap), wave-scan of 128 bins, reorder in LDS, coalesced writeback of
// src-only entries. Exports nodeoff[] (absolute) and ndeg[] per node.
// ---------------------------------------------------------------------------
__global__ __launch_bounds__(256) void bucket_sort(unsigned* __restrict__ bkt,
                                                   const int* __restrict__ gcur,
                                                   int* __restrict__ ndeg,
                                                   int* __restrict__ nodeoff,
                                                   int n_nodes) {
    __shared__ unsigned ent[BKT_CAP];   // 12 KB
    __shared__ unsigned srt[BKT_CAP];   // 12 KB
    __shared__ int hist[R_NODES];
    __shared__ int base[R_NODES];

    int b = blockIdx.x, tid = threadIdx.x;
    int ecnt = min(gcur[b], BKT_CAP);
    unsigned* gb = bkt + (size_t)b * BKT_CAP;

    if (tid < R_NODES) hist[tid] = 0;
    __syncthreads();

    for (int i = tid; i < ecnt; i += 256) {
        unsigned v = gb[i];
        ent[i] = v;
        atomicAdd(&hist[v & 127u], 1);
    }
    __syncthreads();

    // exclusive scan of 128 bins by wave 0 (2 bins/lane)
    if (tid < 64) {
        int a = hist[2 * tid], bb = hist[2 * tid + 1];
        int s = a + bb;
        int sc = s;
        for (int off = 1; off < 64; off <<= 1) {
            int v = __shfl_up(sc, off, 64);
            if (tid >= off) sc += v;
        }
        int excl = sc - s;
        base[2 * tid] = excl;
        base[2 * tid + 1] = excl + a;
    }
    __syncthreads();

    // export CSR meta (before base becomes a cursor)
    int n0 = b * R_NODES;
    if (tid < R_NODES && n0 + tid < n_nodes) {
        ndeg[n0 + tid]    = hist[tid];
        nodeoff[n0 + tid] = b * BKT_CAP + base[tid];
    }
    __syncthreads();

    // reorder: scatter into srt via cursor atomics (int, LDS)
    for (int i = tid; i < ecnt; i += 256) {
        unsigned v = ent[i];
        int p = atomicAdd(&base[v & 127u], 1);
        srt[p] = v >> 7;                 // keep src only
    }
    __syncthreads();

    // coalesced in-place writeback
    for (int i = tid; i < ecnt; i += 256) gb[i] = srt[i];
}

// ---------------------------------------------------------------------------
// Stage 3: tmp(fp16) = (feat * outdeg^-1/2) @ W.  4 rows x 4 cols/thread.
// ---------------------------------------------------------------------------
__global__ __launch_bounds__(256) void linear_kernel(const float* __restrict__ feat,
                                                     const float* __restrict__ weight,
                                                     const int* __restrict__ out_cnt,
                                                     __half* __restrict__ tmp, int n_nodes) {
    __shared__ float w[IN_F * OUT_F];
    {
        const float4* wg = (const float4*)weight;
        float4* wsh = (float4*)w;
        for (int i = threadIdx.x; i < IN_F * OUT_F / 4; i += 256) wsh[i] = wg[i];
    }
    __syncthreads();

    int q  = threadIdx.x >> 3;
    int cg = threadIdx.x & 7;
    int row0 = blockIdx.x * 128 + q * 4;
    if (row0 >= n_nodes) return;
    int rmax = n_nodes - row0;
    if (rmax > 4) rmax = 4;

    const float4* feat4 = (const float4*)feat;
    float4 acc[4];
#pragma unroll
    for (int r = 0; r < 4; ++r) acc[r] = make_float4(0.f, 0.f, 0.f, 0.f);

    for (int k4 = 0; k4 < IN_F / 4; ++k4) {
        float4 wv0 = *(const float4*)&w[(4 * k4 + 0) * OUT_F + 4 * cg];
        float4 wv1 = *(const float4*)&w[(4 * k4 + 1) * OUT_F + 4 * cg];
        float4 wv2 = *(const float4*)&w[(4 * k4 + 2) * OUT_F + 4 * cg];
        float4 wv3 = *(const float4*)&w[(4 * k4 + 3) * OUT_F + 4 * cg];
#pragma unroll
        for (int r = 0; r < 4; ++r) {
            int rr = (r < rmax) ? r : 0;
            float4 f = feat4[(size_t)(row0 + rr) * (IN_F / 4) + k4];
            acc[r].x += f.x * wv0.x + f.y * wv1.x + f.z * wv2.x + f.w * wv3.x;
            acc[r].y += f.x * wv0.y + f.y * wv1.y + f.z * wv2.y + f.w * wv3.y;
            acc[r].z += f.x * wv0.z + f.y * wv1.z + f.z * wv2.z + f.w * wv3.z;
            acc[r].w += f.x * wv0.w + f.y * wv1.w + f.z * wv2.w + f.w * wv3.w;
        }
    }

#pragma unroll
    for (int r = 0; r < 4; ++r) {
        if (r < rmax) {
            float sc = rsqrtf(fmaxf((float)out_cnt[row0 + r], 1.0f));
            union { __half h[4]; uint2 u; } pk;
            pk.h[0] = __float2half(acc[r].x * sc);
            pk.h[1] = __float2half(acc[r].y * sc);
            pk.h[2] = __float2half(acc[r].z * sc);
            pk.h[3] = __float2half(acc[r].w * sc);
            *(uint2*)&tmp[(size_t)(row0 + r) * OUT_F + 4 * cg] = pk.u;
        }
    }
}

// ---------------------------------------------------------------------------
// Stage 4: CSR gather, NO atomics (round-6 lesson: ds_add_f32 streams cap
// at ~4.6 cyc/lane — the 350us wall). One 32-lane group per node; edge srcs
// loaded coalesced once per 32, broadcast via shfl(width=32); 4 independent
// tmp-row loads in flight; fp32 register sum; one scaled coalesced write.
// ---------------------------------------------------------------------------
__global__ __launch_bounds__(256) void csr_gather(const unsigned* __restrict__ bkt,
                                                  const int* __restrict__ nodeoff,
                                                  const int* __restrict__ ndeg,
                                                  const int* __restrict__ in_cnt,
                                                  const __half* __restrict__ tmp,
                                                  float* __restrict__ out, int n_nodes) {
    int t = blockIdx.x * 256 + threadIdx.x;
    int node = t >> 5;
    int c = t & 31;
    if (node >= n_nodes) return;

    int start = nodeoff[node];
    int cnt = ndeg[node];

    float a0 = 0.f, a1 = 0.f, a2 = 0.f, a3 = 0.f;
    int j = 0;
    while (j < cnt) {
        int chunk = min(cnt - j, 32);
        int sidx = 0;
        if (c < chunk) sidx = (int)bkt[start + j + c];   // coalesced
        int jj = 0;
        for (; jj + 4 <= chunk; jj += 4) {
            int s0 = __shfl(sidx, jj + 0, 32);
            int s1 = __shfl(sidx, jj + 1, 32);
            int s2 = __shfl(sidx, jj + 2, 32);
            int s3 = __shfl(sidx, jj + 3, 32);
            float v0 = __half2float(tmp[(size_t)s0 * OUT_F + c]);
            float v1 = __half2float(tmp[(size_t)s1 * OUT_F + c]);
            float v2 = __half2float(tmp[(size_t)s2 * OUT_F + c]);
            float v3 = __half2float(tmp[(size_t)s3 * OUT_F + c]);
            a0 += v0; a1 += v1; a2 += v2; a3 += v3;
        }
        for (; jj < chunk; ++jj) {
            int s = __shfl(sidx, jj, 32);
            a0 += __half2float(tmp[(size_t)s * OUT_F + c]);
        }
        j += chunk;
    }

    float dg = (float)(cnt + in_cnt[node]);
    float sc = rsqrtf(fmaxf(dg, 1.0f));
    out[(size_t)node * OUT_F + c] = (a0 + a1 + a2 + a3) * sc;
}

// ---------------------------------------------------------------------------
// Stage 4b: overflow edges — expected 0; correctness only.
// ---------------------------------------------------------------------------
__global__ void ovf_kernel(const int* __restrict__ ovf, const int* __restrict__ ovf_cnt,
                           const int* __restrict__ ndeg, const int* __restrict__ in_cnt,
                           const __half* __restrict__ tmp, float* __restrict__ out) {
    int t = blockIdx.x * blockDim.x + threadIdx.x;
    int e = t >> 5, c = t & 31;
    int n = min(*ovf_cnt, OVF_CAP);
    if (e < n) {
        int s = ovf[2 * e], d = ovf[2 * e + 1];
        float scale = rsqrtf(fmaxf((float)(ndeg[d] + in_cnt[d]), 1.0f));
        atomicAdd(&out[(size_t)d * OUT_F + c],
                  __half2float(tmp[(size_t)s * OUT_F + c]) * scale);
    }
}

// ---------------------------------------------------------------------------
// Fallback (ws too small): atomic scatter path.
// ---------------------------------------------------------------------------
__global__ void scatter_kernel(const int* __restrict__ src, const int* __restrict__ dst,
                               const __half* __restrict__ tmp, float* __restrict__ out,
                               int n_edges) {
    long long t = (long long)blockIdx.x * blockDim.x + threadIdx.x;
    int e = (int)(t >> 5);
    int c = (int)(t & (OUT_F - 1));
    if (e < n_edges) {
        atomicAdd(&out[(size_t)dst[e] * OUT_F + c],
                  __half2float(tmp[(size_t)src[e] * OUT_F + c]));
    }
}

__global__ void finalize_kernel(float* __restrict__ out, const int* __restrict__ in_cnt,
                                int n_total) {
    int t = blockIdx.x * blockDim.x + threadIdx.x;
    if (t < n_total) {
        out[t] *= rsqrtf(fmaxf((float)in_cnt[t >> 5], 1.0f));
    }
}

__global__ void degree_kernel(const int* __restrict__ src, const int* __restrict__ dst,
                              int* __restrict__ out_cnt, int* __restrict__ in_cnt,
                              int n_edges) {
    int i = blockIdx.x * blockDim.x + threadIdx.x;
    if (i < n_edges) {
        atomicAdd(&out_cnt[src[i]], 1);
        atomicAdd(&in_cnt[dst[i]], 1);
    }
}

extern "C" void kernel_launch(void* const* d_in, const int* in_sizes, int n_in,
                              void* d_out, int out_size, void* d_ws, size_t ws_size,
                              hipStream_t stream) {
    const float* feat   = (const float*)d_in[0];
    const int*   src    = (const int*)d_in[1];
    const int*   dst    = (const int*)d_in[2];
    const float* weight = (const float*)d_in[3];
    float*       out    = (float*)d_out;

    int n_nodes = in_sizes[0] / IN_F;   // 100000
    int n_edges = in_sizes[1];          // 1600000
    int n_buckets = (n_nodes + R_NODES - 1) / R_NODES;  // 782 (<= MAXNB)

    // ws layout: [out_cnt n][in_cnt n][gcur MAXNB][ovf_cnt 8][ovf 2*CAP]
    //            [bkt nb*BKT_CAP][tmp fp16 n*32][ndeg n][nodeoff n]
    int*      out_cnt = (int*)d_ws;
    int*      in_cnt  = out_cnt + n_nodes;
    int*      gcur    = in_cnt + n_nodes;
    int*      ovf_cnt = gcur + MAXNB;
    int*      ovf     = ovf_cnt + 8;
    unsigned* bkt     = (unsigned*)(ovf + 2 * OVF_CAP);
    __half*   tmp     = (__half*)(bkt + (size_t)n_buckets * BKT_CAP);
    int*      ndeg    = (int*)(tmp + (size_t)n_nodes * OUT_F);
    int*      nodeoff = ndeg + n_nodes;
    size_t    needed  = (char*)(nodeoff + n_nodes) - (char*)d_ws;

    if (ws_size >= needed && n_buckets <= MAXNB) {
        hipMemsetAsync(out_cnt, 0, ((size_t)2 * n_nodes + MAXNB + 8) * sizeof(int), stream);
        build_kernel<<<(n_edges + EPB - 1) / EPB, 256, 0, stream>>>(
            src, dst, out_cnt, in_cnt, gcur, bkt, ovf, ovf_cnt, n_edges);
        bucket_sort<<<n_buckets, 256, 0, stream>>>(bkt, gcur, ndeg, nodeoff, n_nodes);
        linear_kernel<<<(n_nodes + 127) / 128, 256, 0, stream>>>(
            feat, weight, out_cnt, tmp, n_nodes);
        csr_gather<<<((size_t)n_nodes * 32 + 255) / 256, 256, 0, stream>>>(
            bkt, nodeoff, ndeg, in_cnt, tmp, out, n_nodes);
        ovf_kernel<<<OVF_CAP * 32 / 256, 256, 0, stream>>>(ovf, ovf_cnt, ndeg, in_cnt, tmp, out);
    } else {
        // fallback: atomic scatter
        __half* tmp_fb = (__half*)(ovf + 2 * OVF_CAP);
        hipMemsetAsync(out_cnt, 0, ((size_t)2 * n_nodes + MAXNB + 8) * sizeof(int), stream);
        hipMemsetAsync(d_out, 0, (size_t)out_size * sizeof(float), stream);
        degree_kernel<<<(n_edges + 255) / 256, 256, 0, stream>>>(src, dst, out_cnt, in_cnt, n_edges);
        linear_kernel<<<(n_nodes + 127) / 128, 256, 0, stream>>>(feat, weight, out_cnt, tmp_fb, n_nodes);
        long long st = (long long)n_edges * OUT_F;
        scatter_kernel<<<(int)((st + 255) / 256), 256, 0, stream>>>(src, dst, tmp_fb, out, n_edges);
        finalize_kernel<<<(n_nodes * OUT_F + 255) / 256, 256, 0, stream>>>(out, in_cnt, n_nodes * OUT_F);
    }
}

// Round 8
// 228.012 us; speedup vs baseline: 2.5323x; 1.0776x over previous
//
#include <hip/hip_runtime.h>
#include <hip/hip_fp16.h>

#define IN_F 128
#define OUT_F 32
#define R_NODES 128          // dst nodes per bucket (7 bits)
#define BKT_CAP 3072         // Poisson(2046)+23sigma; overflow handled anyway
#define OVF_CAP 4096
#define EPB 8192             // edges per build block
#define MAXNB 1024           // max buckets => n_nodes <= 131072

// ---------------------------------------------------------------------------
// Stage 1: src-degrees + bucket partition via BLOCK-LOCAL counting sort.
// Round-3 lesson: never grid-scatter 4B grains; chunked flush only.
// Round-7 lesson: 196 blocks x 4 waves starves the grid (7.5% occupancy) —
// 1024 threads/block gives each pass 16 waves; grid stays 196 so chunk
// sizes (write-amplification) are unchanged.
// in_cnt counts ONLY overflow edges; main in-degree comes from bucket_sort.
// ---------------------------------------------------------------------------
__global__ __launch_bounds__(1024) void build_kernel(
    const int* __restrict__ src, const int* __restrict__ dst,
    int* __restrict__ out_cnt, int* __restrict__ in_cnt,
    int* __restrict__ gcur, unsigned* __restrict__ bkt,
    int* __restrict__ ovf, int* __restrict__ ovf_cnt,
    int n_edges) {

    __shared__ unsigned sorted[EPB];        // 32 KB
    __shared__ unsigned short binof[EPB];   // 16 KB
    __shared__ int hist[MAXNB];             // 4 KB: count, then cursor
    __shared__ int lbase[MAXNB];            // 4 KB
    __shared__ int gbase[MAXNB];            // 4 KB
    __shared__ int wsum[16];

    int tid = threadIdx.x;
    int e0 = blockIdx.x * EPB;
    int ecnt = min(EPB, n_edges - e0);

    hist[tid] = 0;                          // one bin per thread
    __syncthreads();

    // pass 1: src-degree atomics + bin histogram
    for (int k = tid; k < ecnt; k += 1024) {
        int e = e0 + k;
        int s = src[e], d = dst[e];
        atomicAdd(&out_cnt[s], 1);
        atomicAdd(&hist[d >> 7], 1);
    }
    __syncthreads();

    // block-wide exclusive scan (1 bin/thread): wave-scan + 16-partial fixup
    int cnt = hist[tid];
    int lane = tid & 63, wid = tid >> 6;
    int scan = cnt;
    for (int off = 1; off < 64; off <<= 1) {
        int v = __shfl_up(scan, off, 64);
        if (lane >= off) scan += v;
    }
    if (lane == 63) wsum[wid] = scan;
    __syncthreads();
    int woff = 0;
    for (int w = 0; w < wid; ++w) woff += wsum[w];
    int excl = woff + scan - cnt;
    lbase[tid] = excl;
    hist[tid]  = excl;                      // becomes insertion cursor
    if (cnt > 0) gbase[tid] = atomicAdd(&gcur[tid], cnt);
    __syncthreads();

    // pass 2: local counting-sort into LDS (edges re-read, L2/L3-hot)
    for (int k = tid; k < ecnt; k += 1024) {
        int e = e0 + k;
        int s = src[e], d = dst[e];
        int bin = d >> 7;
        int idx = atomicAdd(&hist[bin], 1);
        sorted[idx] = ((unsigned)s << 7) | (unsigned)(d & 127);
        binof[idx]  = (unsigned short)bin;
    }
    __syncthreads();

    // pass 3: chunked, mostly-coalesced flush
    for (int i = tid; i < ecnt; i += 1024) {
        unsigned v = sorted[i];
        int bin = binof[i];
        int gpos = gbase[bin] + (i - lbase[bin]);
        if (gpos < BKT_CAP) {
            bkt[(size_t)bin * BKT_CAP + gpos] = v;
        } else {
            int d = bin * R_NODES + (int)(v & 127);
            atomicAdd(&in_cnt[d], 1);       // overflow-only in-degree
            int o = atomicAdd(ovf_cnt, 1);
            if (o < OVF_CAP) {
                ovf[2 * o]     = (int)(v >> 7);
                ovf[2 * o + 1] = d;
            }
        }
    }
}

// ---------------------------------------------------------------------------
// Stage 2: per-bucket sort by local dst -> in-place CSR. One block/bucket.
// Int LDS atomics only (round-6 lesson: no fp LDS-atomic streams).
// Exports nodeoff[] (absolute) and ndeg[] per node.
// ---------------------------------------------------------------------------
__global__ __launch_bounds__(512) void bucket_sort(unsigned* __restrict__ bkt,
                                                   const int* __restrict__ gcur,
                                                   int* __restrict__ ndeg,
                                                   int* __restrict__ nodeoff,
                                                   int n_nodes) {
    __shared__ unsigned ent[BKT_CAP];   // 12 KB
    __shared__ unsigned srt[BKT_CAP];   // 12 KB
    __shared__ int hist[R_NODES];
    __shared__ int base[R_NODES];

    int b = blockIdx.x, tid = threadIdx.x;
    int ecnt = min(gcur[b], BKT_CAP);
    unsigned* gb = bkt + (size_t)b * BKT_CAP;

    if (tid < R_NODES) hist[tid] = 0;
    __syncthreads();

    for (int i = tid; i < ecnt; i += 512) {
        unsigned v = gb[i];
        ent[i] = v;
        atomicAdd(&hist[v & 127u], 1);
    }
    __syncthreads();

    // exclusive scan of 128 bins by wave 0 (2 bins/lane)
    if (tid < 64) {
        int a = hist[2 * tid], bb = hist[2 * tid + 1];
        int s = a + bb;
        int sc = s;
        for (int off = 1; off < 64; off <<= 1) {
            int v = __shfl_up(sc, off, 64);
            if (tid >= off) sc += v;
        }
        int excl = sc - s;
        base[2 * tid] = excl;
        base[2 * tid + 1] = excl + a;
    }
    __syncthreads();

    // export CSR meta (before base becomes a cursor)
    int n0 = b * R_NODES;
    if (tid < R_NODES && n0 + tid < n_nodes) {
        ndeg[n0 + tid]    = hist[tid];
        nodeoff[n0 + tid] = b * BKT_CAP + base[tid];
    }
    __syncthreads();

    // reorder: scatter into srt via cursor atomics (int, LDS)
    for (int i = tid; i < ecnt; i += 512) {
        unsigned v = ent[i];
        int p = atomicAdd(&base[v & 127u], 1);
        srt[p] = v >> 7;                 // keep src only
    }
    __syncthreads();

    // coalesced in-place writeback
    for (int i = tid; i < ecnt; i += 512) gb[i] = srt[i];
}

// ---------------------------------------------------------------------------
// Stage 3: tmp(fp16) = (feat * outdeg^-1/2) @ W.  4 rows x 4 cols/thread.
// ---------------------------------------------------------------------------
__global__ __launch_bounds__(256) void linear_kernel(const float* __restrict__ feat,
                                                     const float* __restrict__ weight,
                                                     const int* __restrict__ out_cnt,
                                                     __half* __restrict__ tmp, int n_nodes) {
    __shared__ float w[IN_F * OUT_F];
    {
        const float4* wg = (const float4*)weight;
        float4* wsh = (float4*)w;
        for (int i = threadIdx.x; i < IN_F * OUT_F / 4; i += 256) wsh[i] = wg[i];
    }
    __syncthreads();

    int q  = threadIdx.x >> 3;
    int cg = threadIdx.x & 7;
    int row0 = blockIdx.x * 128 + q * 4;
    if (row0 >= n_nodes) return;
    int rmax = n_nodes - row0;
    if (rmax > 4) rmax = 4;

    const float4* feat4 = (const float4*)feat;
    float4 acc[4];
#pragma unroll
    for (int r = 0; r < 4; ++r) acc[r] = make_float4(0.f, 0.f, 0.f, 0.f);

    for (int k4 = 0; k4 < IN_F / 4; ++k4) {
        float4 wv0 = *(const float4*)&w[(4 * k4 + 0) * OUT_F + 4 * cg];
        float4 wv1 = *(const float4*)&w[(4 * k4 + 1) * OUT_F + 4 * cg];
        float4 wv2 = *(const float4*)&w[(4 * k4 + 2) * OUT_F + 4 * cg];
        float4 wv3 = *(const float4*)&w[(4 * k4 + 3) * OUT_F + 4 * cg];
#pragma unroll
        for (int r = 0; r < 4; ++r) {
            int rr = (r < rmax) ? r : 0;
            float4 f = feat4[(size_t)(row0 + rr) * (IN_F / 4) + k4];
            acc[r].x += f.x * wv0.x + f.y * wv1.x + f.z * wv2.x + f.w * wv3.x;
            acc[r].y += f.x * wv0.y + f.y * wv1.y + f.z * wv2.y + f.w * wv3.y;
            acc[r].z += f.x * wv0.z + f.y * wv1.z + f.z * wv2.z + f.w * wv3.z;
            acc[r].w += f.x * wv0.w + f.y * wv1.w + f.z * wv2.w + f.w * wv3.w;
        }
    }

#pragma unroll
    for (int r = 0; r < 4; ++r) {
        if (r < rmax) {
            float sc = rsqrtf(fmaxf((float)out_cnt[row0 + r], 1.0f));
            union { __half h[4]; uint2 u; } pk;
            pk.h[0] = __float2half(acc[r].x * sc);
            pk.h[1] = __float2half(acc[r].y * sc);
            pk.h[2] = __float2half(acc[r].z * sc);
            pk.h[3] = __float2half(acc[r].w * sc);
            *(uint2*)&tmp[(size_t)(row0 + r) * OUT_F + 4 * cg] = pk.u;
        }
    }
}

// ---------------------------------------------------------------------------
// Stage 4: CSR gather, NO atomics (round-6 lesson). One 32-lane group per
// node; srcs loaded coalesced, broadcast via shfl(width=32); 4 independent
// tmp-row loads in flight; fp32 register sum; one scaled coalesced write.
// ---------------------------------------------------------------------------
__global__ __launch_bounds__(256) void csr_gather(const unsigned* __restrict__ bkt,
                                                  const int* __restrict__ nodeoff,
                                                  const int* __restrict__ ndeg,
                                                  const int* __restrict__ in_cnt,
                                                  const __half* __restrict__ tmp,
                                                  float* __restrict__ out, int n_nodes) {
    int t = blockIdx.x * 256 + threadIdx.x;
    int node = t >> 5;
    int c = t & 31;
    if (node >= n_nodes) return;

    int start = nodeoff[node];
    int cnt = ndeg[node];

    float a0 = 0.f, a1 = 0.f, a2 = 0.f, a3 = 0.f;
    int j = 0;
    while (j < cnt) {
        int chunk = min(cnt - j, 32);
        int sidx = 0;
        if (c < chunk) sidx = (int)bkt[start + j + c];   // coalesced
        int jj = 0;
        for (; jj + 4 <= chunk; jj += 4) {
            int s0 = __shfl(sidx, jj + 0, 32);
            int s1 = __shfl(sidx, jj + 1, 32);
            int s2 = __shfl(sidx, jj + 2, 32);
            int s3 = __shfl(sidx, jj + 3, 32);
            float v0 = __half2float(tmp[(size_t)s0 * OUT_F + c]);
            float v1 = __half2float(tmp[(size_t)s1 * OUT_F + c]);
            float v2 = __half2float(tmp[(size_t)s2 * OUT_F + c]);
            float v3 = __half2float(tmp[(size_t)s3 * OUT_F + c]);
            a0 += v0; a1 += v1; a2 += v2; a3 += v3;
        }
        for (; jj < chunk; ++jj) {
            int s = __shfl(sidx, jj, 32);
            a0 += __half2float(tmp[(size_t)s * OUT_F + c]);
        }
        j += chunk;
    }

    float dg = (float)(cnt + in_cnt[node]);
    float sc = rsqrtf(fmaxf(dg, 1.0f));
    out[(size_t)node * OUT_F + c] = (a0 + a1 + a2 + a3) * sc;
}

// ---------------------------------------------------------------------------
// Stage 4b: overflow edges — expected 0; correctness only.
// ---------------------------------------------------------------------------
__global__ void ovf_kernel(const int* __restrict__ ovf, const int* __restrict__ ovf_cnt,
                           const int* __restrict__ ndeg, const int* __restrict__ in_cnt,
                           const __half* __restrict__ tmp, float* __restrict__ out) {
    int t = blockIdx.x * blockDim.x + threadIdx.x;
    int e = t >> 5, c = t & 31;
    int n = min(*ovf_cnt, OVF_CAP);
    if (e < n) {
        int s = ovf[2 * e], d = ovf[2 * e + 1];
        float scale = rsqrtf(fmaxf((float)(ndeg[d] + in_cnt[d]), 1.0f));
        atomicAdd(&out[(size_t)d * OUT_F + c],
                  __half2float(tmp[(size_t)s * OUT_F + c]) * scale);
    }
}

// ---------------------------------------------------------------------------
// Fallback (ws too small): atomic scatter path.
// ---------------------------------------------------------------------------
__global__ void scatter_kernel(const int* __restrict__ src, const int* __restrict__ dst,
                               const __half* __restrict__ tmp, float* __restrict__ out,
                               int n_edges) {
    long long t = (long long)blockIdx.x * blockDim.x + threadIdx.x;
    int e = (int)(t >> 5);
    int c = (int)(t & (OUT_F - 1));
    if (e < n_edges) {
        atomicAdd(&out[(size_t)dst[e] * OUT_F + c],
                  __half2float(tmp[(size_t)src[e] * OUT_F + c]));
    }
}

__global__ void finalize_kernel(float* __restrict__ out, const int* __restrict__ in_cnt,
                                int n_total) {
    int t = blockIdx.x * blockDim.x + threadIdx.x;
    if (t < n_total) {
        out[t] *= rsqrtf(fmaxf((float)in_cnt[t >> 5], 1.0f));
    }
}

__global__ void degree_kernel(const int* __restrict__ src, const int* __restrict__ dst,
                              int* __restrict__ out_cnt, int* __restrict__ in_cnt,
                              int n_edges) {
    int i = blockIdx.x * blockDim.x + threadIdx.x;
    if (i < n_edges) {
        atomicAdd(&out_cnt[src[i]], 1);
        atomicAdd(&in_cnt[dst[i]], 1);
    }
}

extern "C" void kernel_launch(void* const* d_in, const int* in_sizes, int n_in,
                              void* d_out, int out_size, void* d_ws, size_t ws_size,
                              hipStream_t stream) {
    const float* feat   = (const float*)d_in[0];
    const int*   src    = (const int*)d_in[1];
    const int*   dst    = (const int*)d_in[2];
    const float* weight = (const float*)d_in[3];
    float*       out    = (float*)d_out;

    int n_nodes = in_sizes[0] / IN_F;   // 100000
    int n_edges = in_sizes[1];          // 1600000
    int n_buckets = (n_nodes + R_NODES - 1) / R_NODES;  // 782 (<= MAXNB)

    // ws layout: [out_cnt n][in_cnt n][gcur MAXNB][ovf_cnt 8][ovf 2*CAP]
    //            [bkt nb*BKT_CAP][tmp fp16 n*32][ndeg n][nodeoff n]
    int*      out_cnt = (int*)d_ws;
    int*      in_cnt  = out_cnt + n_nodes;
    int*      gcur    = in_cnt + n_nodes;
    int*      ovf_cnt = gcur + MAXNB;
    int*      ovf     = ovf_cnt + 8;
    unsigned* bkt     = (unsigned*)(ovf + 2 * OVF_CAP);
    __half*   tmp     = (__half*)(bkt + (size_t)n_buckets * BKT_CAP);
    int*      ndeg    = (int*)(tmp + (size_t)n_nodes * OUT_F);
    int*      nodeoff = ndeg + n_nodes;
    size_t    needed  = (char*)(nodeoff + n_nodes) - (char*)d_ws;

    if (ws_size >= needed && n_buckets <= MAXNB) {
        hipMemsetAsync(out_cnt, 0, ((size_t)2 * n_nodes + MAXNB + 8) * sizeof(int), stream);
        build_kernel<<<(n_edges + EPB - 1) / EPB, 1024, 0, stream>>>(
            src, dst, out_cnt, in_cnt, gcur, bkt, ovf, ovf_cnt, n_edges);
        bucket_sort<<<n_buckets, 512, 0, stream>>>(bkt, gcur, ndeg, nodeoff, n_nodes);
        linear_kernel<<<(n_nodes + 127) / 128, 256, 0, stream>>>(
            feat, weight, out_cnt, tmp, n_nodes);
        csr_gather<<<((size_t)n_nodes * 32 + 255) / 256, 256, 0, stream>>>(
            bkt, nodeoff, ndeg, in_cnt, tmp, out, n_nodes);
        ovf_kernel<<<OVF_CAP * 32 / 256, 256, 0, stream>>>(ovf, ovf_cnt, ndeg, in_cnt, tmp, out);
    } else {
        // fallback: atomic scatter
        __half* tmp_fb = (__half*)(ovf + 2 * OVF_CAP);
        hipMemsetAsync(out_cnt, 0, ((size_t)2 * n_nodes + MAXNB + 8) * sizeof(int), stream);
        hipMemsetAsync(d_out, 0, (size_t)out_size * sizeof(float), stream);
        degree_kernel<<<(n_edges + 255) / 256, 256, 0, stream>>>(src, dst, out_cnt, in_cnt, n_edges);
        linear_kernel<<<(n_nodes + 127) / 128, 256, 0, stream>>>(feat, weight, out_cnt, tmp_fb, n_nodes);
        long long st = (long long)n_edges * OUT_F;
        scatter_kernel<<<(int)((st + 255) / 256), 256, 0, stream>>>(src, dst, tmp_fb, out, n_edges);
        finalize_kernel<<<(n_nodes * OUT_F + 255) / 256, 256, 0, stream>>>(out, in_cnt, n_nodes * OUT_F);
    }
}